// Round 4
// baseline (1016.404 us; speedup 1.0000x reference)
//
#include <hip/hip_runtime.h>
#include <hip/hip_bf16.h>
#include <stdint.h>

#define T_ 128
#define B_ 8
#define V_ 32000
#define E_ 128
#define H_ 256
#define N_ 20
#define M_ 1024        // B*T rows
#define NCH 500        // V/64 column chunks
#define LDA 68         // padded LDS leading dim

// ---------- whT[j][i] = W_h[i][j] (for coalesced scan weight loads) ----------
__global__ void whT_k(const float* __restrict__ Wh, float* __restrict__ whT) {
  int idx = blockIdx.x*256 + threadIdx.x;   // 65536
  int i = idx >> 8, j = idx & 255;
  whT[j*H_ + i] = Wh[i*H_ + j];
}

// ---------- einv[v] = 1/max(||emb[v]||, 1e-8) ----------
__global__ void prep_k(const float* __restrict__ emb, float* __restrict__ einv) {
  int v = blockIdx.x, l = threadIdx.x;  // 64 threads
  float e0 = emb[v*E_ + l];
  float e1 = emb[v*E_ + 64 + l];
  float ss = e0*e0 + e1*e1;
  #pragma unroll
  for (int off = 32; off >= 1; off >>= 1) ss += __shfl_xor(ss, off);
  if (l == 0) einv[v] = 1.f / fmaxf(sqrtf(ss), 1e-8f);
}

// ---------- WiT[e][i] = W_i[i][e] ----------
__global__ void wit_k(const float* __restrict__ Wi, float* __restrict__ WiT) {
  int idx = blockIdx.x*256 + threadIdx.x;
  if (idx < H_*E_) {
    int i = idx >> 7, e = idx & (E_-1);
    WiT[e*H_ + i] = Wi[idx];
  }
}

// ---------- RI[r][i] = (l2norm(emb[x_ids]) @ W_i.T)[i] ----------
__global__ __launch_bounds__(256) void ri_k(const int* __restrict__ x_ids,
    const float* __restrict__ emb, const float* __restrict__ WiT,
    float* __restrict__ RI)
{
  __shared__ float xn[E_];
  __shared__ float red[2];
  int r = blockIdx.x, tid = threadIdx.x;
  int id = x_ids[r];
  float v = 0.f;
  if (tid < E_) v = emb[id*E_ + tid];
  float ss = v*v;
  if (tid < E_) {
    #pragma unroll
    for (int off = 32; off >= 1; off >>= 1) ss += __shfl_xor(ss, off);
    if ((tid & 63) == 0) red[tid >> 6] = ss;
  }
  __syncthreads();
  float inv = 1.f / fmaxf(sqrtf(red[0] + red[1]), 1e-12f);
  if (tid < E_) xn[tid] = v*inv;
  __syncthreads();
  float s = 0.f;
  for (int e = 0; e < E_; ++e) s += xn[e]*WiT[e*H_ + tid];
  RI[r*H_ + tid] = s;
}

// ---------- sequential scan: 1024 threads, W_h fp32 in VGPRs (64/thread) ----------
__global__ __launch_bounds__(1024) void scan_k(
    const int* __restrict__ x_ids, const float* __restrict__ emb,
    const float* __restrict__ whT, const float* __restrict__ W_ops,
    const float* __restrict__ W_ch, const float* __restrict__ sharp,
    const float* __restrict__ RI,
    float* __restrict__ HM, float* __restrict__ PVN, float* __restrict__ CH)
{
  __shared__ float hlds[H_];
  __shared__ float hred[4*H_];
  __shared__ float stck[N_*E_];
  __shared__ float ptrs[N_], nptr[N_], wpsh[N_];
  __shared__ float xi[E_];
  __shared__ float wof[3*H_], wcf[2*H_];
  __shared__ float dred[24];
  __shared__ float scal[8];

  const int b = blockIdx.x, tid = threadIdx.x;
  const int q = tid >> 8, i = tid & 255;

  float wreg[64];                              // W_h[i][q*64+u], coalesced via whT
  #pragma unroll
  for (int u = 0; u < 64; ++u) wreg[u] = whT[(q*64 + u)*H_ + i];

  if (tid < H_) {
    #pragma unroll
    for (int k = 0; k < 3; ++k) wof[k*H_ + tid] = W_ops[k*2*H_ + tid] + W_ops[k*2*H_ + H_ + tid];
    #pragma unroll
    for (int k = 0; k < 2; ++k) wcf[k*H_ + tid] = W_ch[k*2*H_ + tid] + W_ch[k*2*H_ + H_ + tid];
    hlds[tid] = 0.f;
  }
  for (int m = tid; m < N_*E_; m += 1024) stck[m] = 0.001f;
  if (tid < N_) ptrs[tid] = (tid == 0) ? 1.f : 0.f;
  const float sh = sharp[0];
  __syncthreads();

  for (int t = 0; t < T_; ++t) {
    const int r = b*T_ + t;
    // P1: 4-way-split matvec h @ W_h^T (weights in regs, h broadcast from LDS)
    {
      float p = 0.f;
      #pragma unroll
      for (int u = 0; u < 64; ++u) p += wreg[u]*hlds[q*64 + u];
      hred[q*H_ + i] = p;
    }
    __syncthreads();
    // P2/P3: finish h + small dots; pop_val; xi gather (disjoint thread ranges)
    float hm_i = 0.f, pvreg = 0.f;
    if (tid < H_) {
      float s = RI[r*H_ + tid] + hred[tid] + hred[H_+tid] + hred[2*H_+tid] + hred[3*H_+tid];
      float hn = tanhf(s);
      hlds[tid] = hn;                          // next read is P1(t+1), barriered
      hm_i = 1.f - fmaxf(hn, 0.f);
      HM[r*H_ + tid] = hm_i;
      float d0 = hm_i*wof[tid], d1 = hm_i*wof[H_+tid], d2 = hm_i*wof[2*H_+tid];
      float d3 = hm_i*wcf[tid], d4 = hm_i*wcf[H_+tid];
      #pragma unroll
      for (int off = 32; off >= 1; off >>= 1) {
        d0 += __shfl_xor(d0, off); d1 += __shfl_xor(d1, off); d2 += __shfl_xor(d2, off);
        d3 += __shfl_xor(d3, off); d4 += __shfl_xor(d4, off);
      }
      if ((tid & 63) == 0) {
        int w = tid >> 6;
        dred[w] = d0; dred[4+w] = d1; dred[8+w] = d2; dred[12+w] = d3; dred[16+w] = d4;
      }
    } else if (tid < H_ + E_) {                // 256..383: pop_val (old ptr/stack)
      int e = tid - H_;
      float p = 0.f;
      #pragma unroll
      for (int n = 0; n < N_; ++n) p += ptrs[n]*stck[n*E_ + e];
      pvreg = p;
    } else if (tid < H_ + 2*E_) {              // 384..511: xi = emb[x_ids[b,t]]
      int e = tid - H_ - E_;
      int id = x_ids[b*T_ + t];
      xi[e] = emb[id*E_ + e];
    }
    __syncthreads();
    // P4: tiny softmaxes; pop_val sumsq
    if (tid == 0) {
      float o0 = dred[0]+dred[1]+dred[2]+dred[3];
      float o1 = dred[4]+dred[5]+dred[6]+dred[7];
      float o2 = dred[8]+dred[9]+dred[10]+dred[11];
      float q0 = dred[12]+dred[13]+dred[14]+dred[15];
      float q1 = dred[16]+dred[17]+dred[18]+dred[19];
      float mx = fmaxf(o0, fmaxf(o1, o2));
      float e0 = expf(o0-mx), e1 = expf(o1-mx), e2 = expf(o2-mx);
      float inv = 1.f/(e0+e1+e2);
      scal[0] = e0*inv; scal[1] = e1*inv; scal[2] = e2*inv;   // push, pop, nop
      float cm = fmaxf(q0, q1);
      float f0 = expf(q0-cm), f1 = expf(q1-cm);
      float ci = 1.f/(f0+f1);
      scal[3] = f0*ci; scal[4] = f1*ci;                       // choice
    }
    if (tid >= H_ && tid < H_ + E_) {
      float ssq = pvreg*pvreg;
      #pragma unroll
      for (int off = 32; off >= 1; off >>= 1) ssq += __shfl_xor(ssq, off);
      if ((tid & 63) == 0) dred[20 + ((tid >> 6) - 4)] = ssq;
    }
    __syncthreads();
    // P5: pv norm scale; ptr roll + pow
    if (tid == 0) scal[5] = 1.f / fmaxf(sqrtf(dred[20] + dred[21]), 1e-8f);
    if (tid >= 64 && tid < 64 + N_) {
      int n = tid - 64;
      float push = scal[0], pop = scal[1], nop = scal[2];
      float pp = ptrs[(n + N_ - 1) % N_];
      float po = ptrs[(n + 1) % N_];
      float raw = push*pp + pop*po + nop*ptrs[n];
      nptr[n] = powf(fmaxf(raw, 1e-8f), sh);
      wpsh[n] = push*pp;
    }
    __syncthreads();
    // P6: stack blend; PVN/CH writes; ptr-sum
    for (int m = tid; m < N_*E_; m += 1024) {
      int n = m >> 7, e = m & (E_-1);
      float w = wpsh[n];
      stck[m] = stck[m]*(1.f - w) + w*xi[e];
    }
    if (tid >= H_ && tid < H_ + E_) PVN[r*E_ + (tid - H_)] = pvreg*scal[5];
    if (tid == 448) { CH[r*2] = scal[3]; CH[r*2+1] = scal[4]; }
    if (tid == 449) {
      float s = 0.f;
      for (int n = 0; n < N_; ++n) s += nptr[n];
      scal[6] = 1.f/s;
    }
    __syncthreads();
    // P7: normalize ptr
    if (tid < N_) ptrs[tid] = nptr[tid]*scal[6];
    __syncthreads();
  }
}

// ---------- pass A: logits GEMM -> per-(row, 64-col-chunk) max & sumexp ----------
__global__ __launch_bounds__(256) void stats_k(const float* __restrict__ HM,
    const float* __restrict__ W_fc, float* __restrict__ SM, float* __restrict__ SS)
{
  __shared__ __align__(16) float As[16*LDA];
  __shared__ __align__(16) float Bs[16*LDA];
  const int tid = threadIdx.x;
  const int tn = tid & 15, tm = tid >> 4;
  const int Rb = blockIdx.y*64, Cb = blockIdx.x*64;
  const int lk = tid & 15, lr = tid >> 4;
  float acc[4][4] = {};
  for (int k0 = 0; k0 < H_; k0 += 16) {
    #pragma unroll
    for (int rr = 0; rr < 4; ++rr) {
      int m = lr + 16*rr;
      As[lk*LDA + m] = HM[(Rb+m)*H_ + k0 + lk];
      Bs[lk*LDA + m] = W_fc[(Cb+m)*2*H_ + k0 + lk] + W_fc[(Cb+m)*2*H_ + H_ + k0 + lk];
    }
    __syncthreads();
    #pragma unroll
    for (int k = 0; k < 16; ++k) {
      float4 a4 = *reinterpret_cast<const float4*>(&As[k*LDA + tm*4]);
      float4 b4 = *reinterpret_cast<const float4*>(&Bs[k*LDA + tn*4]);
      float av[4] = {a4.x, a4.y, a4.z, a4.w};
      float bv[4] = {b4.x, b4.y, b4.z, b4.w};
      #pragma unroll
      for (int a = 0; a < 4; ++a)
        #pragma unroll
        for (int c = 0; c < 4; ++c) acc[a][c] += av[a]*bv[c];
    }
    __syncthreads();
  }
  #pragma unroll
  for (int a = 0; a < 4; ++a) {
    float mx = fmaxf(fmaxf(acc[a][0], acc[a][1]), fmaxf(acc[a][2], acc[a][3]));
    #pragma unroll
    for (int off = 1; off < 16; off <<= 1) mx = fmaxf(mx, __shfl_xor(mx, off));
    float sm = expf(acc[a][0]-mx) + expf(acc[a][1]-mx) + expf(acc[a][2]-mx) + expf(acc[a][3]-mx);
    #pragma unroll
    for (int off = 1; off < 16; off <<= 1) sm += __shfl_xor(sm, off);
    if (tn == 0) {
      int row = Rb + tm*4 + a;
      SM[row*NCH + blockIdx.x] = mx;
      SS[row*NCH + blockIdx.x] = sm;
    }
  }
}

// ---------- combine per-chunk stats -> per-row (max, 1/sum) ----------
__global__ void reduce_k(const float* __restrict__ SM, const float* __restrict__ SS,
                         float* __restrict__ MS)
{
  int row = blockIdx.x, l = threadIdx.x;  // 64 threads
  float m = -1e30f;
  for (int c = l; c < NCH; c += 64) m = fmaxf(m, SM[row*NCH + c]);
  #pragma unroll
  for (int off = 32; off >= 1; off >>= 1) m = fmaxf(m, __shfl_xor(m, off));
  float s = 0.f;
  for (int c = l; c < NCH; c += 64) s += SS[row*NCH + c]*expf(SM[row*NCH + c] - m);
  #pragma unroll
  for (int off = 32; off >= 1; off >>= 1) s += __shfl_xor(s, off);
  if (l == 0) { MS[row*2] = m; MS[row*2+1] = 1.f/s; }
}

// ---------- pass B: recompute logits + syntactic GEMM, combine, store fp32 ----------
__global__ __launch_bounds__(256) void final_k(const float* __restrict__ HM,
    const float* __restrict__ W_fc, const float* __restrict__ PVN,
    const float* __restrict__ emb, const float* __restrict__ einv,
    const float* __restrict__ MS, const float* __restrict__ CH,
    float* __restrict__ out)
{
  __shared__ __align__(16) float As[16*LDA];
  __shared__ __align__(16) float Bs[16*LDA];
  const int tid = threadIdx.x;
  const int tn = tid & 15, tm = tid >> 4;
  const int Rb = blockIdx.y*64, Cb = blockIdx.x*64;
  const int lk = tid & 15, lr = tid >> 4;
  float accL[4][4] = {};
  float accS[4][4] = {};
  for (int k0 = 0; k0 < H_; k0 += 16) {            // semantic logits, K=256
    #pragma unroll
    for (int rr = 0; rr < 4; ++rr) {
      int m = lr + 16*rr;
      As[lk*LDA + m] = HM[(Rb+m)*H_ + k0 + lk];
      Bs[lk*LDA + m] = W_fc[(Cb+m)*2*H_ + k0 + lk] + W_fc[(Cb+m)*2*H_ + H_ + k0 + lk];
    }
    __syncthreads();
    #pragma unroll
    for (int k = 0; k < 16; ++k) {
      float4 a4 = *reinterpret_cast<const float4*>(&As[k*LDA + tm*4]);
      float4 b4 = *reinterpret_cast<const float4*>(&Bs[k*LDA + tn*4]);
      float av[4] = {a4.x, a4.y, a4.z, a4.w};
      float bv[4] = {b4.x, b4.y, b4.z, b4.w};
      #pragma unroll
      for (int a = 0; a < 4; ++a)
        #pragma unroll
        for (int c = 0; c < 4; ++c) accL[a][c] += av[a]*bv[c];
    }
    __syncthreads();
  }
  for (int k0 = 0; k0 < E_; k0 += 16) {            // syntactic, K=128
    #pragma unroll
    for (int rr = 0; rr < 4; ++rr) {
      int m = lr + 16*rr;
      As[lk*LDA + m] = PVN[(Rb+m)*E_ + k0 + lk];
      Bs[lk*LDA + m] = emb[(Cb+m)*E_ + k0 + lk] * einv[Cb+m];
    }
    __syncthreads();
    #pragma unroll
    for (int k = 0; k < 16; ++k) {
      float4 a4 = *reinterpret_cast<const float4*>(&As[k*LDA + tm*4]);
      float4 b4 = *reinterpret_cast<const float4*>(&Bs[k*LDA + tn*4]);
      float av[4] = {a4.x, a4.y, a4.z, a4.w};
      float bv[4] = {b4.x, b4.y, b4.z, b4.w};
      #pragma unroll
      for (int a = 0; a < 4; ++a)
        #pragma unroll
        for (int c = 0; c < 4; ++c) accS[a][c] += av[a]*bv[c];
    }
    __syncthreads();
  }
  #pragma unroll
  for (int a = 0; a < 4; ++a) {
    int row = Rb + tm*4 + a;
    float M  = MS[row*2],  Si = MS[row*2+1];
    float c0 = CH[row*2],  c1 = CH[row*2+1];
    float4 v;
    v.x = c0*expf(accL[a][0]-M)*Si + c1*accS[a][0];
    v.y = c0*expf(accL[a][1]-M)*Si + c1*accS[a][1];
    v.z = c0*expf(accL[a][2]-M)*Si + c1*accS[a][2];
    v.w = c0*expf(accL[a][3]-M)*Si + c1*accS[a][3];
    *reinterpret_cast<float4*>(&out[(size_t)row*V_ + Cb + tn*4]) = v;
  }
}

extern "C" void kernel_launch(void* const* d_in, const int* in_sizes, int n_in,
                              void* d_out, int out_size, void* d_ws, size_t ws_size,
                              hipStream_t stream) {
  const int*   x_ids = (const int*)d_in[0];
  const float* emb   = (const float*)d_in[1];
  const float* W_i   = (const float*)d_in[2];
  const float* W_h   = (const float*)d_in[3];
  const float* W_fc  = (const float*)d_in[4];
  const float* W_ops = (const float*)d_in[5];
  const float* W_ch  = (const float*)d_in[6];
  const float* sharp = (const float*)d_in[7];
  float* out = (float*)d_out;

  float* ws   = (float*)d_ws;          // ~7.1 MB total
  float* whT  = ws;                    // 65536
  float* einv = whT + 65536;           // 32000
  float* WiT  = einv + 32000;          // 32768
  float* RI   = WiT + 32768;           // 262144
  float* HM   = RI + 262144;           // 262144
  float* PVN  = HM + 262144;           // 131072
  float* CH   = PVN + 131072;          // 2048
  float* SM   = CH + 2048;             // 512000
  float* SS   = SM + 512000;           // 512000
  float* MS   = SS + 512000;           // 2048

  whT_k<<<H_*H_/256, 256, 0, stream>>>(W_h, whT);
  prep_k<<<V_, 64, 0, stream>>>(emb, einv);
  wit_k<<<(H_*E_ + 255)/256, 256, 0, stream>>>(W_i, WiT);
  ri_k<<<M_, 256, 0, stream>>>(x_ids, emb, WiT, RI);
  scan_k<<<B_, 1024, 0, stream>>>(x_ids, emb, whT, W_ops, W_ch, sharp, RI, HM, PVN, CH);
  stats_k<<<dim3(NCH, M_/64), 256, 0, stream>>>(HM, W_fc, SM, SS);
  reduce_k<<<M_, 64, 0, stream>>>(SM, SS, MS);
  final_k<<<dim3(NCH, M_/64), 256, 0, stream>>>(HM, W_fc, PVN, emb, einv, MS, CH, out);
}

// Round 5
// 545.042 us; speedup vs baseline: 1.8648x; 1.8648x over previous
//
#include <hip/hip_runtime.h>
#include <hip/hip_bf16.h>
#include <stdint.h>

#define T_ 128
#define B_ 8
#define V_ 32000
#define E_ 128
#define H_ 256
#define N_ 20
#define M_ 1024        // B*T rows
#define PIT 264        // LDS pitch (shorts) for K=256 tiles
#define PIT2 136       // LDS pitch (shorts) for K=128 tiles
#define NCH2 1000      // V/32 stat chunks

typedef __attribute__((ext_vector_type(8))) short short8;
typedef __attribute__((ext_vector_type(4))) float f32x4;
typedef unsigned short ushort;

static __device__ __forceinline__ ushort f2bf_u(float f) {
  __hip_bfloat16 h = __float2bfloat16(f);
  return *reinterpret_cast<ushort*>(&h);
}

// ---------- whT[j][i] = W_h[i][j] ----------
__global__ void whT_k(const float* __restrict__ Wh, float* __restrict__ whT) {
  int idx = blockIdx.x*256 + threadIdx.x;   // 65536
  int i = idx >> 8, j = idx & 255;
  whT[j*H_ + i] = Wh[i*H_ + j];
}

// ---------- WiT[e][i] = W_i[i][e] ----------
__global__ void wit_k(const float* __restrict__ Wi, float* __restrict__ WiT) {
  int idx = blockIdx.x*256 + threadIdx.x;
  if (idx < H_*E_) {
    int i = idx >> 7, e = idx & (E_-1);
    WiT[e*H_ + i] = Wi[idx];
  }
}

// ---------- embnb[v][e] = bf16(emb[v][e]/max(||emb[v]||,1e-8)) ----------
__global__ void embn_k(const float* __restrict__ emb, ushort* __restrict__ embnb) {
  int v = blockIdx.x, l = threadIdx.x;  // 64 threads
  float e0 = emb[v*E_ + l];
  float e1 = emb[v*E_ + 64 + l];
  float ss = e0*e0 + e1*e1;
  #pragma unroll
  for (int off = 32; off >= 1; off >>= 1) ss += __shfl_xor(ss, off);
  float inv = 1.f / fmaxf(sqrtf(ss), 1e-8f);
  embnb[v*E_ + l]      = f2bf_u(e0*inv);
  embnb[v*E_ + 64 + l] = f2bf_u(e1*inv);
}

// ---------- Wfcb[n][k] = bf16(W_fc[n][k] + W_fc[n][256+k]) ----------
__global__ void foldfc_k(const float* __restrict__ Wfc, ushort* __restrict__ Wfcb) {
  int idx = blockIdx.x*256 + threadIdx.x;   // 8,192,000
  int n = idx >> 8, k = idx & 255;
  Wfcb[idx] = f2bf_u(Wfc[n*2*H_ + k] + Wfc[n*2*H_ + H_ + k]);
}

// ---------- RI[r][i] = (l2norm(emb[x_ids]) @ W_i.T)[i] ----------
__global__ __launch_bounds__(256) void ri_k(const int* __restrict__ x_ids,
    const float* __restrict__ emb, const float* __restrict__ WiT,
    float* __restrict__ RI)
{
  __shared__ float xn[E_];
  __shared__ float red[2];
  int r = blockIdx.x, tid = threadIdx.x;
  int id = x_ids[r];
  float v = 0.f;
  if (tid < E_) v = emb[id*E_ + tid];
  float ss = v*v;
  if (tid < E_) {
    #pragma unroll
    for (int off = 32; off >= 1; off >>= 1) ss += __shfl_xor(ss, off);
    if ((tid & 63) == 0) red[tid >> 6] = ss;
  }
  __syncthreads();
  float inv = 1.f / fmaxf(sqrtf(red[0] + red[1]), 1e-12f);
  if (tid < E_) xn[tid] = v*inv;
  __syncthreads();
  float s = 0.f;
  for (int e = 0; e < E_; ++e) s += xn[e]*WiT[e*H_ + tid];
  RI[r*H_ + tid] = s;
}

// ---------- sequential scan (unchanged math; emits bf16 HMb/PVNb) ----------
__global__ __launch_bounds__(1024) void scan_k(
    const int* __restrict__ x_ids, const float* __restrict__ emb,
    const float* __restrict__ whT, const float* __restrict__ W_ops,
    const float* __restrict__ W_ch, const float* __restrict__ sharp,
    const float* __restrict__ RI,
    ushort* __restrict__ HMb, ushort* __restrict__ PVNb, float* __restrict__ CH)
{
  __shared__ float hlds[H_];
  __shared__ float hred[4*H_];
  __shared__ float stck[N_*E_];
  __shared__ float ptrs[N_], nptr[N_], wpsh[N_];
  __shared__ float xi[E_];
  __shared__ float wof[3*H_], wcf[2*H_];
  __shared__ float dred[24];
  __shared__ float scal[8];

  const int b = blockIdx.x, tid = threadIdx.x;
  const int q = tid >> 8, i = tid & 255;

  float wreg[64];
  #pragma unroll
  for (int u = 0; u < 64; ++u) wreg[u] = whT[(q*64 + u)*H_ + i];

  if (tid < H_) {
    #pragma unroll
    for (int k = 0; k < 3; ++k) wof[k*H_ + tid] = W_ops[k*2*H_ + tid] + W_ops[k*2*H_ + H_ + tid];
    #pragma unroll
    for (int k = 0; k < 2; ++k) wcf[k*H_ + tid] = W_ch[k*2*H_ + tid] + W_ch[k*2*H_ + H_ + tid];
    hlds[tid] = 0.f;
  }
  for (int m = tid; m < N_*E_; m += 1024) stck[m] = 0.001f;
  if (tid < N_) ptrs[tid] = (tid == 0) ? 1.f : 0.f;
  const float sh = sharp[0];
  __syncthreads();

  for (int t = 0; t < T_; ++t) {
    const int r = b*T_ + t;
    {
      float p = 0.f;
      #pragma unroll
      for (int u = 0; u < 64; ++u) p += wreg[u]*hlds[q*64 + u];
      hred[q*H_ + i] = p;
    }
    __syncthreads();
    float hm_i = 0.f, pvreg = 0.f;
    if (tid < H_) {
      float s = RI[r*H_ + tid] + hred[tid] + hred[H_+tid] + hred[2*H_+tid] + hred[3*H_+tid];
      float hn = tanhf(s);
      hlds[tid] = hn;
      hm_i = 1.f - fmaxf(hn, 0.f);
      HMb[r*H_ + tid] = f2bf_u(hm_i);
      float d0 = hm_i*wof[tid], d1 = hm_i*wof[H_+tid], d2 = hm_i*wof[2*H_+tid];
      float d3 = hm_i*wcf[tid], d4 = hm_i*wcf[H_+tid];
      #pragma unroll
      for (int off = 32; off >= 1; off >>= 1) {
        d0 += __shfl_xor(d0, off); d1 += __shfl_xor(d1, off); d2 += __shfl_xor(d2, off);
        d3 += __shfl_xor(d3, off); d4 += __shfl_xor(d4, off);
      }
      if ((tid & 63) == 0) {
        int w = tid >> 6;
        dred[w] = d0; dred[4+w] = d1; dred[8+w] = d2; dred[12+w] = d3; dred[16+w] = d4;
      }
    } else if (tid < H_ + E_) {
      int e = tid - H_;
      float p = 0.f;
      #pragma unroll
      for (int n = 0; n < N_; ++n) p += ptrs[n]*stck[n*E_ + e];
      pvreg = p;
    } else if (tid < H_ + 2*E_) {
      int e = tid - H_ - E_;
      int id = x_ids[b*T_ + t];
      xi[e] = emb[id*E_ + e];
    }
    __syncthreads();
    if (tid == 0) {
      float o0 = dred[0]+dred[1]+dred[2]+dred[3];
      float o1 = dred[4]+dred[5]+dred[6]+dred[7];
      float o2 = dred[8]+dred[9]+dred[10]+dred[11];
      float q0 = dred[12]+dred[13]+dred[14]+dred[15];
      float q1 = dred[16]+dred[17]+dred[18]+dred[19];
      float mx = fmaxf(o0, fmaxf(o1, o2));
      float e0 = expf(o0-mx), e1 = expf(o1-mx), e2 = expf(o2-mx);
      float inv = 1.f/(e0+e1+e2);
      scal[0] = e0*inv; scal[1] = e1*inv; scal[2] = e2*inv;
      float cm = fmaxf(q0, q1);
      float f0 = expf(q0-cm), f1 = expf(q1-cm);
      float ci = 1.f/(f0+f1);
      scal[3] = f0*ci; scal[4] = f1*ci;
    }
    if (tid >= H_ && tid < H_ + E_) {
      float ssq = pvreg*pvreg;
      #pragma unroll
      for (int off = 32; off >= 1; off >>= 1) ssq += __shfl_xor(ssq, off);
      if ((tid & 63) == 0) dred[20 + ((tid >> 6) - 4)] = ssq;
    }
    __syncthreads();
    if (tid == 0) scal[5] = 1.f / fmaxf(sqrtf(dred[20] + dred[21]), 1e-8f);
    if (tid >= 64 && tid < 64 + N_) {
      int n = tid - 64;
      float push = scal[0], pop = scal[1], nop = scal[2];
      float pp = ptrs[(n + N_ - 1) % N_];
      float po = ptrs[(n + 1) % N_];
      float raw = push*pp + pop*po + nop*ptrs[n];
      nptr[n] = powf(fmaxf(raw, 1e-8f), sh);
      wpsh[n] = push*pp;
    }
    __syncthreads();
    for (int m = tid; m < N_*E_; m += 1024) {
      int n = m >> 7, e = m & (E_-1);
      float w = wpsh[n];
      stck[m] = stck[m]*(1.f - w) + w*xi[e];
    }
    if (tid >= H_ && tid < H_ + E_) PVNb[r*E_ + (tid - H_)] = f2bf_u(pvreg*scal[5]);
    if (tid == 448) { CH[r*2] = scal[3]; CH[r*2+1] = scal[4]; }
    if (tid == 449) {
      float s = 0.f;
      for (int n = 0; n < N_; ++n) s += nptr[n];
      scal[6] = 1.f/s;
    }
    __syncthreads();
    if (tid < N_) ptrs[tid] = nptr[tid]*scal[6];
    __syncthreads();
  }
}

// ================= MFMA GEMM passes =================
// Block: 256 thr = 4 waves (2x2). Tile 64(M)x64(N), full K in LDS.
// Wave (wr,wc) owns 32x32; per-wave 2x2 16x16 MFMA subtiles.
// Fragment k-map: k = g*8 + j (g = lane>>4), identical for A and B
// -> MFMA dot is k-permutation invariant. C/D: col=lane&15, row=g*4+reg.

// ---------- pass A: semantic logits -> per-(row, 32-col-chunk) sumexp ----------
__global__ __launch_bounds__(256) void stats2_k(const ushort* __restrict__ HMb,
    const ushort* __restrict__ Wfcb, float* __restrict__ SS)
{
  __shared__ __align__(16) ushort As[64*PIT];
  __shared__ __align__(16) ushort Bs[64*PIT];
  const int tid = threadIdx.x;
  const int Rb = blockIdx.y*64, Cb = blockIdx.x*64;
  const uint4* srcA = (const uint4*)(HMb  + (size_t)Rb*H_);
  const uint4* srcB = (const uint4*)(Wfcb + (size_t)Cb*H_);
  #pragma unroll
  for (int it = 0; it < 8; ++it) {
    int idx = it*256 + tid, row = idx >> 5, c = idx & 31;
    *(uint4*)&As[row*PIT + c*8] = srcA[row*32 + c];
    *(uint4*)&Bs[row*PIT + c*8] = srcB[row*32 + c];
  }
  __syncthreads();

  const int wave = tid >> 6, lane = tid & 63;
  const int wr = wave >> 1, wc = wave & 1;
  const int lr = lane & 15, g = lane >> 4;
  f32x4 acc[2][2] = {};
  const ushort* Ab = &As[(wr*32 + lr)*PIT + g*8];
  const ushort* Bb = &Bs[(wc*32 + lr)*PIT + g*8];
  #pragma unroll
  for (int ks = 0; ks < 8; ++ks) {
    short8 a0 = *(const short8*)(Ab + ks*32);
    short8 a1 = *(const short8*)(Ab + 16*PIT + ks*32);
    short8 b0 = *(const short8*)(Bb + ks*32);
    short8 b1 = *(const short8*)(Bb + 16*PIT + ks*32);
    acc[0][0] = __builtin_amdgcn_mfma_f32_16x16x32_bf16(a0, b0, acc[0][0], 0, 0, 0);
    acc[0][1] = __builtin_amdgcn_mfma_f32_16x16x32_bf16(a0, b1, acc[0][1], 0, 0, 0);
    acc[1][0] = __builtin_amdgcn_mfma_f32_16x16x32_bf16(a1, b0, acc[1][0], 0, 0, 0);
    acc[1][1] = __builtin_amdgcn_mfma_f32_16x16x32_bf16(a1, b1, acc[1][1], 0, 0, 0);
  }
  const int chunk = blockIdx.x*2 + wc;
  #pragma unroll
  for (int mi = 0; mi < 2; ++mi)
    #pragma unroll
    for (int r = 0; r < 4; ++r) {
      float s = expf(acc[mi][0][r]) + expf(acc[mi][1][r]);
      #pragma unroll
      for (int off = 1; off < 16; off <<= 1) s += __shfl_xor(s, off);
      if (lr == 0) SS[(size_t)(Rb + wr*32 + mi*16 + g*4 + r)*NCH2 + chunk] = s;
    }
}

// ---------- combine chunk sums -> MS[row] = 1/sumexp ----------
__global__ void reduce2_k(const float* __restrict__ SS, float* __restrict__ MS) {
  int row = blockIdx.x, l = threadIdx.x;  // 64 threads
  float s = 0.f;
  for (int c = l; c < NCH2; c += 64) s += SS[(size_t)row*NCH2 + c];
  #pragma unroll
  for (int off = 32; off >= 1; off >>= 1) s += __shfl_xor(s, off);
  if (l == 0) MS[row] = 1.f/s;
}

// ---------- pass B: logits (recompute) + syntactic, combine, store fp32 ----------
__global__ __launch_bounds__(256) void final2_k(const ushort* __restrict__ HMb,
    const ushort* __restrict__ Wfcb, const ushort* __restrict__ PVNb,
    const ushort* __restrict__ embnb, const float* __restrict__ MS,
    const float* __restrict__ CH, float* __restrict__ out)
{
  __shared__ __align__(16) ushort As[64*PIT];
  __shared__ __align__(16) ushort Bs[64*PIT];
  const int tid = threadIdx.x;
  const int Rb = blockIdx.y*64, Cb = blockIdx.x*64;
  const int wave = tid >> 6, lane = tid & 63;
  const int wr = wave >> 1, wc = wave & 1;
  const int lr = lane & 15, g = lane >> 4;

  // semantic logits, K=256 (identical codepath to stats2_k -> bitwise-same logits)
  {
    const uint4* srcA = (const uint4*)(HMb  + (size_t)Rb*H_);
    const uint4* srcB = (const uint4*)(Wfcb + (size_t)Cb*H_);
    #pragma unroll
    for (int it = 0; it < 8; ++it) {
      int idx = it*256 + tid, row = idx >> 5, c = idx & 31;
      *(uint4*)&As[row*PIT + c*8] = srcA[row*32 + c];
      *(uint4*)&Bs[row*PIT + c*8] = srcB[row*32 + c];
    }
  }
  __syncthreads();
  f32x4 accL[2][2] = {};
  {
    const ushort* Ab = &As[(wr*32 + lr)*PIT + g*8];
    const ushort* Bb = &Bs[(wc*32 + lr)*PIT + g*8];
    #pragma unroll
    for (int ks = 0; ks < 8; ++ks) {
      short8 a0 = *(const short8*)(Ab + ks*32);
      short8 a1 = *(const short8*)(Ab + 16*PIT + ks*32);
      short8 b0 = *(const short8*)(Bb + ks*32);
      short8 b1 = *(const short8*)(Bb + 16*PIT + ks*32);
      accL[0][0] = __builtin_amdgcn_mfma_f32_16x16x32_bf16(a0, b0, accL[0][0], 0, 0, 0);
      accL[0][1] = __builtin_amdgcn_mfma_f32_16x16x32_bf16(a0, b1, accL[0][1], 0, 0, 0);
      accL[1][0] = __builtin_amdgcn_mfma_f32_16x16x32_bf16(a1, b0, accL[1][0], 0, 0, 0);
      accL[1][1] = __builtin_amdgcn_mfma_f32_16x16x32_bf16(a1, b1, accL[1][1], 0, 0, 0);
    }
  }
  __syncthreads();   // all waves done reading before re-staging

  // syntactic, K=128
  {
    const uint4* srcA = (const uint4*)(PVNb  + (size_t)Rb*E_);
    const uint4* srcB = (const uint4*)(embnb + (size_t)Cb*E_);
    #pragma unroll
    for (int it = 0; it < 4; ++it) {
      int idx = it*256 + tid, row = idx >> 4, c = idx & 15;
      *(uint4*)&As[row*PIT2 + c*8] = srcA[row*16 + c];
      *(uint4*)&Bs[row*PIT2 + c*8] = srcB[row*16 + c];
    }
  }
  __syncthreads();
  f32x4 accS[2][2] = {};
  {
    const ushort* Ab = &As[(wr*32 + lr)*PIT2 + g*8];
    const ushort* Bb = &Bs[(wc*32 + lr)*PIT2 + g*8];
    #pragma unroll
    for (int ks = 0; ks < 4; ++ks) {
      short8 a0 = *(const short8*)(Ab + ks*32);
      short8 a1 = *(const short8*)(Ab + 16*PIT2 + ks*32);
      short8 b0 = *(const short8*)(Bb + ks*32);
      short8 b1 = *(const short8*)(Bb + 16*PIT2 + ks*32);
      accS[0][0] = __builtin_amdgcn_mfma_f32_16x16x32_bf16(a0, b0, accS[0][0], 0, 0, 0);
      accS[0][1] = __builtin_amdgcn_mfma_f32_16x16x32_bf16(a0, b1, accS[0][1], 0, 0, 0);
      accS[1][0] = __builtin_amdgcn_mfma_f32_16x16x32_bf16(a1, b0, accS[1][0], 0, 0, 0);
      accS[1][1] = __builtin_amdgcn_mfma_f32_16x16x32_bf16(a1, b1, accS[1][1], 0, 0, 0);
    }
  }

  #pragma unroll
  for (int mi = 0; mi < 2; ++mi)
    #pragma unroll
    for (int r = 0; r < 4; ++r) {
      int row = Rb + wr*32 + mi*16 + g*4 + r;
      float Si = MS[row];
      float c0 = CH[row*2], c1 = CH[row*2+1];
      float v0 = c0*expf(accL[mi][0][r])*Si + c1*accS[mi][0][r];
      float v1 = c0*expf(accL[mi][1][r])*Si + c1*accS[mi][1][r];
      size_t base = (size_t)row*V_ + Cb + wc*32 + lr;
      out[base]      = v0;
      out[base + 16] = v1;
    }
}

extern "C" void kernel_launch(void* const* d_in, const int* in_sizes, int n_in,
                              void* d_out, int out_size, void* d_ws, size_t ws_size,
                              hipStream_t stream) {
  const int*   x_ids = (const int*)d_in[0];
  const float* emb   = (const float*)d_in[1];
  const float* W_i   = (const float*)d_in[2];
  const float* W_h   = (const float*)d_in[3];
  const float* W_fc  = (const float*)d_in[4];
  const float* W_ops = (const float*)d_in[5];
  const float* W_ch  = (const float*)d_in[6];
  const float* sharp = (const float*)d_in[7];
  float* out = (float*)d_out;

  float* ws    = (float*)d_ws;             // ~31 MB total
  float*  whT  = ws;                       // 65536
  float*  WiT  = whT + 65536;              // 32768
  float*  RI   = WiT + 32768;              // 262144
  float*  CH   = RI + 262144;              // 2048
  float*  MS   = CH + 2048;                // 1024
  float*  SS   = MS + 1024;                // 1,024,000
  float*  fend = SS + 1024000;
  ushort* HMb   = (ushort*)fend;           // 262144 shorts
  ushort* PVNb  = HMb + 262144;            // 131072
  ushort* Wfcb  = PVNb + 131072;           // 8,192,000
  ushort* embnb = Wfcb + 8192000;          // 4,096,000

  whT_k  <<<H_*H_/256, 256, 0, stream>>>(W_h, whT);
  wit_k  <<<(H_*E_ + 255)/256, 256, 0, stream>>>(W_i, WiT);
  embn_k <<<V_, 64, 0, stream>>>(emb, embnb);
  foldfc_k<<<V_*H_/256, 256, 0, stream>>>(W_fc, Wfcb);
  ri_k   <<<M_, 256, 0, stream>>>(x_ids, emb, WiT, RI);
  scan_k <<<B_, 1024, 0, stream>>>(x_ids, emb, whT, W_ops, W_ch, sharp, RI, HMb, PVNb, CH);
  stats2_k<<<dim3(V_/64, M_/64), 256, 0, stream>>>(HMb, Wfcb, SS);
  reduce2_k<<<M_, 64, 0, stream>>>(SS, MS);
  final2_k<<<dim3(V_/64, M_/64), 256, 0, stream>>>(HMb, Wfcb, PVNb, embnb, MS, CH, out);
}